// Round 1
// baseline (452.315 us; speedup 1.0000x reference)
//
#include <hip/hip_runtime.h>

// ---------------------------------------------------------------------------
// TopKPooling (PyG-style) fused pipeline for MI355X.
// Fixed problem shape: G=256 graphs, N=2048 nodes/graph, D=128, E=4194304,
// DE=16, ratio=0.5 -> k=1024 kept nodes per graph.
//
// Outputs (concatenated flat float32 in d_out):
//   x_out        [G*k, 128]
//   edge_index_out [2, E]   (-1 for dropped edges; stored as float)
//   edge_attr_out  [E, 16]  (0 for dropped edges)
//   batch_out      [G*k]
//   edge_mask      [E]      (0/1 as float)
//
// Correctness-critical: top-k ordering must match a float64 numpy reference.
// Scores are computed in double; tanh is monotone so ordering == ordering of
// the f64 dot product. Ties broken by lower index (lax.top_k semantics).
// ---------------------------------------------------------------------------

// K1: per-node score = tanh((x . w) / ||w||), double precision.
// One wave (64 lanes) per node; lane reads float2 (8B) of x and w.
__global__ __launch_bounds__(256) void score_kernel(
    const float* __restrict__ x, const float* __restrict__ w,
    double* __restrict__ scores, int n_total) {
  int wave = (int)((blockIdx.x * (unsigned)blockDim.x + threadIdx.x) >> 6);
  int lane = threadIdx.x & 63;
  if (wave >= n_total) return;
  const float2 xv = *reinterpret_cast<const float2*>(x + (size_t)wave * 128 + lane * 2);
  const float2 wv = *reinterpret_cast<const float2*>(w + lane * 2);
  double dot = (double)xv.x * (double)wv.x + (double)xv.y * (double)wv.y;
  double wsq = (double)wv.x * (double)wv.x + (double)wv.y * (double)wv.y;
  for (int off = 32; off > 0; off >>= 1) {
    dot += __shfl_down(dot, off);
    wsq += __shfl_down(wsq, off);
  }
  if (lane == 0) scores[wave] = tanh(dot / sqrt(wsq));
}

// K2: per-graph bitonic top-k (full sort of 2048 keys in LDS).
// Sort ascending by (~sortable(score), idx) == descending score, ties->low idx.
// Writes perm (rank-ordered global node ids) and node_map (new id or -1).
__global__ __launch_bounds__(256) void topk_kernel(
    const double* __restrict__ scores, int* __restrict__ perm,
    int* __restrict__ node_map, int n, int k) {
  __shared__ unsigned long long skey[2048];
  __shared__ int sidx[2048];
  const int g = blockIdx.x;
  const int tid = threadIdx.x;

  for (int j = tid; j < n; j += 256) {
    double s = scores[(size_t)g * n + j];
    unsigned long long b = (unsigned long long)__double_as_longlong(s);
    // monotone map double -> uint64
    unsigned long long u = (b & 0x8000000000000000ULL) ? ~b : (b | 0x8000000000000000ULL);
    skey[j] = ~u;  // inverted: ascending key == descending score
    sidx[j] = j;
  }

  for (int size = 2; size <= n; size <<= 1) {
    for (int stride = size >> 1; stride > 0; stride >>= 1) {
      __syncthreads();
      for (int t = tid; t < (n >> 1); t += 256) {
        int lo = ((t & ~(stride - 1)) << 1) | (t & (stride - 1));
        int hi = lo + stride;
        bool asc = ((lo & size) == 0);
        unsigned long long ka = skey[lo], kb = skey[hi];
        int ia = sidx[lo], ib = sidx[hi];
        bool hi_lt_lo = (kb < ka) || (kb == ka && ib < ia);
        bool lo_lt_hi = (ka < kb) || (ka == kb && ia < ib);
        if (asc ? hi_lt_lo : lo_lt_hi) {
          skey[lo] = kb; skey[hi] = ka;
          sidx[lo] = ib; sidx[hi] = ia;
        }
      }
    }
  }
  __syncthreads();

  for (int r = tid; r < n; r += 256) {
    int node = g * n + sidx[r];
    if (r < k) {
      perm[g * k + r] = node;
      node_map[node] = g * k + r;
    } else {
      node_map[node] = -1;
    }
  }
}

// K3: x_out[row] = x[perm[row]] * (float)score[perm[row]]; batch_out.
// 32 lanes x float4 per row.
__global__ __launch_bounds__(256) void gather_kernel(
    const float* __restrict__ x, const double* __restrict__ scores,
    const int* __restrict__ perm, float* __restrict__ x_out,
    float* __restrict__ batch_out, int total_rows, int k) {
  int t = (int)(blockIdx.x * (unsigned)blockDim.x + threadIdx.x);
  int row = t >> 5;
  int d4 = t & 31;
  if (row >= total_rows) return;
  int src = perm[row];
  float s = (float)scores[src];
  float4 v = *reinterpret_cast<const float4*>(x + (size_t)src * 128 + d4 * 4);
  v.x *= s; v.y *= s; v.z *= s; v.w *= s;
  *reinterpret_cast<float4*>(x_out + (size_t)row * 128 + d4 * 4) = v;
  if (d4 == 0) batch_out[row] = (float)(row / k);
}

// K4a: edge remap + mask. Random 4B gathers into 2MB node_map (L2-resident).
__global__ __launch_bounds__(256) void edge_idx_kernel(
    const int* __restrict__ edge_index, const int* __restrict__ node_map,
    float* __restrict__ eio, float* __restrict__ mask_out, int E) {
  int e = (int)(blockIdx.x * (unsigned)blockDim.x + threadIdx.x);
  if (e >= E) return;
  int s = edge_index[e];
  int d = edge_index[E + e];
  int ns = node_map[s];
  int nd = node_map[d];
  bool m = (ns >= 0) && (nd >= 0);
  eio[e] = m ? (float)ns : -1.0f;
  eio[E + e] = m ? (float)nd : -1.0f;
  mask_out[e] = m ? 1.0f : 0.0f;
}

// K4b: edge_attr_out = mask ? edge_attr : 0. One float4 per thread (DE=16).
__global__ __launch_bounds__(256) void edge_attr_kernel(
    const float4* __restrict__ attr, const float* __restrict__ mask,
    float4* __restrict__ attr_out, int n4) {
  int idx = (int)(blockIdx.x * (unsigned)blockDim.x + threadIdx.x);
  if (idx >= n4) return;
  float m = mask[idx >> 2];
  float4 a = attr[idx];
  if (m == 0.0f) { a.x = 0.f; a.y = 0.f; a.z = 0.f; a.w = 0.f; }
  attr_out[idx] = a;
}

extern "C" void kernel_launch(void* const* d_in, const int* in_sizes, int n_in,
                              void* d_out, int out_size, void* d_ws, size_t ws_size,
                              hipStream_t stream) {
  const float* x          = (const float*)d_in[0];
  const int*   edge_index = (const int*)d_in[1];
  const float* edge_attr  = (const float*)d_in[2];
  const float* w          = (const float*)d_in[4];

  const int D = 128;
  const int n_total = in_sizes[0] / D;         // 524288
  const int E = in_sizes[1] / 2;               // 4194304
  const int G = 256;
  const int n = n_total / G;                   // 2048
  const int k = (n + 1) / 2;                   // ceil(0.5*n) = 1024
  const int total_rows = G * k;                // 262144

  float* out       = (float*)d_out;
  float* x_out     = out;
  float* eio       = x_out + (size_t)total_rows * D;
  float* attr_out  = eio + (size_t)2 * E;
  float* batch_out = attr_out + (size_t)E * 16;
  float* mask_out  = batch_out + total_rows;

  double* scores = (double*)d_ws;
  int* perm      = (int*)((char*)d_ws + (size_t)n_total * sizeof(double));
  int* node_map  = perm + total_rows;

  score_kernel<<<n_total / 4, 256, 0, stream>>>(x, w, scores, n_total);
  topk_kernel<<<G, 256, 0, stream>>>(scores, perm, node_map, n, k);
  gather_kernel<<<(total_rows * 32) / 256, 256, 0, stream>>>(
      x, scores, perm, x_out, batch_out, total_rows, k);
  edge_idx_kernel<<<(E + 255) / 256, 256, 0, stream>>>(
      edge_index, node_map, eio, mask_out, E);
  int n4 = E * 4;  // 16M float4s
  edge_attr_kernel<<<(n4 + 255) / 256, 256, 0, stream>>>(
      (const float4*)edge_attr, mask_out, (float4*)attr_out, n4);
}

// Round 2
// 375.694 us; speedup vs baseline: 1.2039x; 1.2039x over previous
//
#include <hip/hip_runtime.h>

// ---------------------------------------------------------------------------
// TopKPooling (PyG-style) fused pipeline for MI355X.
// G=256 graphs, N=2048 nodes/graph, D=128, E=4194304, DE=16, k=1024.
//
// Outputs (concatenated flat float32 in d_out):
//   x_out [G*k,128] | edge_index_out [2,E] | edge_attr_out [E,16]
//   batch_out [G*k] | edge_mask [E]
//
// Ordering correctness: top-k rank order must match the f64 numpy reference.
// tanh(dot/||w||) is monotone in dot, so the f64 dot IS the sort key; the
// expensive f64 tanh/sqrt/div are skipped. The f32 gate value only scales
// x_out (huge absmax threshold), so tanhf is fine there.
// ---------------------------------------------------------------------------

// K1: per-node f64 dot (sort key) + f32 gate = tanhf(dot/||w||).
// One wave per node; lane reads float2 of x and w.
__global__ __launch_bounds__(256) void score_kernel(
    const float* __restrict__ x, const float* __restrict__ w,
    double* __restrict__ keys, float* __restrict__ gate, int n_total) {
  int wave = (int)((blockIdx.x * (unsigned)blockDim.x + threadIdx.x) >> 6);
  int lane = threadIdx.x & 63;
  if (wave >= n_total) return;
  const float2 xv = *reinterpret_cast<const float2*>(x + (size_t)wave * 128 + lane * 2);
  const float2 wv = *reinterpret_cast<const float2*>(w + lane * 2);
  double dot = (double)xv.x * (double)wv.x + (double)xv.y * (double)wv.y;
  float wsq = wv.x * wv.x + wv.y * wv.y;
  for (int off = 32; off > 0; off >>= 1) {
    dot += __shfl_down(dot, off);
    wsq += __shfl_down(wsq, off);
  }
  if (lane == 0) {
    keys[wave] = dot;
    gate[wave] = tanhf((float)dot * __frsqrt_rn(wsq));
  }
}

// K2: per-graph bitonic full sort of 2048 f64 keys (descending, ties->low idx).
// 1024 threads: one compare-swap per thread per stage, 66 stages.
__global__ __launch_bounds__(1024) void topk_kernel(
    const double* __restrict__ keys, int* __restrict__ perm,
    int* __restrict__ node_map, int n, int k) {
  __shared__ unsigned long long skey[2048];
  __shared__ int sidx[2048];
  const int g = blockIdx.x;
  const int tid = threadIdx.x;

  for (int j = tid; j < n; j += 1024) {
    unsigned long long b =
        (unsigned long long)__double_as_longlong(keys[(size_t)g * n + j]);
    // monotone double->u64, then invert: ascending u64 == descending score
    unsigned long long u = (b & 0x8000000000000000ULL) ? ~b : (b | 0x8000000000000000ULL);
    skey[j] = ~u;
    sidx[j] = j;
  }

  for (int size = 2; size <= n; size <<= 1) {
    for (int stride = size >> 1; stride > 0; stride >>= 1) {
      __syncthreads();
      int lo = ((tid & ~(stride - 1)) << 1) | (tid & (stride - 1));
      int hi = lo + stride;
      bool asc = ((lo & size) == 0);
      unsigned long long ka = skey[lo], kb = skey[hi];
      int ia = sidx[lo], ib = sidx[hi];
      bool hi_lt_lo = (kb < ka) || (kb == ka && ib < ia);
      if (asc ? hi_lt_lo : !hi_lt_lo && !(ka == kb && ia == ib)) {
        // swap needed when (asc && hi<lo) || (!asc && lo<hi)
        skey[lo] = kb; skey[hi] = ka;
        sidx[lo] = ib; sidx[hi] = ia;
      }
    }
  }
  __syncthreads();

  for (int r = tid; r < n; r += 1024) {
    int node = g * n + sidx[r];
    node_map[node] = (r < k) ? (g * k + r) : -1;
    if (r < k) perm[g * k + r] = node;
  }
}

// K3: x_out[row] = x[perm[row]] * gate[perm[row]]; batch_out.
__global__ __launch_bounds__(256) void gather_kernel(
    const float* __restrict__ x, const float* __restrict__ gate,
    const int* __restrict__ perm, float* __restrict__ x_out,
    float* __restrict__ batch_out, int total_rows, int k) {
  int t = (int)(blockIdx.x * (unsigned)blockDim.x + threadIdx.x);
  int row = t >> 5;
  int d4 = t & 31;
  if (row >= total_rows) return;
  int src = perm[row];
  float s = gate[src];
  float4 v = *reinterpret_cast<const float4*>(x + (size_t)src * 128 + d4 * 4);
  v.x *= s; v.y *= s; v.z *= s; v.w *= s;
  *reinterpret_cast<float4*>(x_out + (size_t)row * 128 + d4 * 4) = v;
  if (d4 == 0) batch_out[row] = (float)(row >> 10);  // k = 1024
}

// K4: fused edge remap + mask + attr gating. One thread per edge.
__global__ __launch_bounds__(256) void edge_kernel(
    const int* __restrict__ edge_index, const int* __restrict__ node_map,
    const float4* __restrict__ attr, float* __restrict__ eio,
    float* __restrict__ mask_out, float4* __restrict__ attr_out, int E) {
  int e = (int)(blockIdx.x * (unsigned)blockDim.x + threadIdx.x);
  if (e >= E) return;
  int ns = node_map[edge_index[e]];
  int nd = node_map[edge_index[E + e]];
  bool m = (ns >= 0) && (nd >= 0);
  float z = m ? 1.0f : 0.0f;
  eio[e] = m ? (float)ns : -1.0f;
  eio[E + e] = m ? (float)nd : -1.0f;
  mask_out[e] = z;
#pragma unroll
  for (int j = 0; j < 4; ++j) {
    float4 a = attr[(size_t)e * 4 + j];
    a.x *= z; a.y *= z; a.z *= z; a.w *= z;
    attr_out[(size_t)e * 4 + j] = a;
  }
}

extern "C" void kernel_launch(void* const* d_in, const int* in_sizes, int n_in,
                              void* d_out, int out_size, void* d_ws, size_t ws_size,
                              hipStream_t stream) {
  const float* x          = (const float*)d_in[0];
  const int*   edge_index = (const int*)d_in[1];
  const float* edge_attr  = (const float*)d_in[2];
  const float* w          = (const float*)d_in[4];

  const int D = 128;
  const int n_total = in_sizes[0] / D;         // 524288
  const int E = in_sizes[1] / 2;               // 4194304
  const int G = 256;
  const int n = n_total / G;                   // 2048
  const int k = (n + 1) / 2;                   // 1024
  const int total_rows = G * k;                // 262144

  float* out       = (float*)d_out;
  float* x_out     = out;
  float* eio       = x_out + (size_t)total_rows * D;
  float* attr_out  = eio + (size_t)2 * E;
  float* batch_out = attr_out + (size_t)E * 16;
  float* mask_out  = batch_out + total_rows;

  double* keys  = (double*)d_ws;                                    // 4 MB
  float* gate   = (float*)((char*)d_ws + (size_t)n_total * 8);      // 2 MB
  int* perm     = (int*)(gate + n_total);                           // 1 MB
  int* node_map = perm + total_rows;                                // 2 MB

  score_kernel<<<n_total / 4, 256, 0, stream>>>(x, w, keys, gate, n_total);
  topk_kernel<<<G, 1024, 0, stream>>>(keys, perm, node_map, n, k);
  gather_kernel<<<(total_rows * 32) / 256, 256, 0, stream>>>(
      x, gate, perm, x_out, batch_out, total_rows, k);
  edge_kernel<<<(E + 255) / 256, 256, 0, stream>>>(
      edge_index, node_map, (const float4*)edge_attr, eio, mask_out,
      (float4*)attr_out, E);
}

// Round 3
// 268.686 us; speedup vs baseline: 1.6834x; 1.3983x over previous
//
#include <hip/hip_runtime.h>

// ---------------------------------------------------------------------------
// TopKPooling (PyG-style) fused pipeline for MI355X.
// G=256 graphs, N=2048 nodes/graph, D=128, E=4194304, DE=16, k=1024.
//
// Outputs (concatenated flat float32 in d_out):
//   x_out [G*k,128] | edge_index_out [2,E] | edge_attr_out [E,16]
//   batch_out [G*k] | edge_mask [E]
//
// Ordering correctness: top-k rank must match the f64 numpy reference.
// tanh(dot/||w||) is monotone in dot, so the f64 dot IS the sort key.
// The f32 gate value only scales x_out (huge absmax threshold) -> tanhf.
// ---------------------------------------------------------------------------

// K1: 32 lanes per node row (float4/lane), 2 nodes per wave.
// f64 dot = sort key; f32 gate = tanhf(dot/||w||).
__global__ __launch_bounds__(256) void score_kernel(
    const float* __restrict__ x, const float* __restrict__ w,
    double* __restrict__ keys, float* __restrict__ gate, int n_total) {
  int t = (int)(blockIdx.x * 256u + threadIdx.x);
  int row = t >> 5;
  int c = (t & 31) * 4;
  if (row >= n_total) return;
  const float4 xv = *reinterpret_cast<const float4*>(x + (size_t)row * 128 + c);
  const float4 wv = *reinterpret_cast<const float4*>(w + c);
  double dot = (double)xv.x * wv.x + (double)xv.y * wv.y +
               (double)xv.z * wv.z + (double)xv.w * wv.w;
  float wsq = wv.x * wv.x + wv.y * wv.y + wv.z * wv.z + wv.w * wv.w;
#pragma unroll
  for (int off = 16; off > 0; off >>= 1) {  // stays within each 32-lane half
    dot += __shfl_xor(dot, off);
    wsq += __shfl_xor(wsq, off);
  }
  if ((t & 31) == 0) {
    keys[row] = dot;
    gate[row] = tanhf((float)dot * __frsqrt_rn(wsq));
  }
}

// K2: per-graph bitonic full sort of 2048 f64 keys (descending, ties->low idx).
// 1024 threads: one compare-swap per thread per stage, 66 stages.
__global__ __launch_bounds__(1024) void topk_kernel(
    const double* __restrict__ keys, int* __restrict__ perm,
    int* __restrict__ node_map, int n, int k) {
  __shared__ unsigned long long skey[2048];
  __shared__ int sidx[2048];
  const int g = blockIdx.x;
  const int tid = threadIdx.x;

  for (int j = tid; j < n; j += 1024) {
    unsigned long long b =
        (unsigned long long)__double_as_longlong(keys[(size_t)g * n + j]);
    // monotone double->u64, inverted: ascending u64 == descending score
    unsigned long long u = (b & 0x8000000000000000ULL) ? ~b : (b | 0x8000000000000000ULL);
    skey[j] = ~u;
    sidx[j] = j;
  }

  for (int size = 2; size <= n; size <<= 1) {
    for (int stride = size >> 1; stride > 0; stride >>= 1) {
      __syncthreads();
      int lo = ((tid & ~(stride - 1)) << 1) | (tid & (stride - 1));
      int hi = lo + stride;
      bool asc = ((lo & size) == 0);
      unsigned long long ka = skey[lo], kb = skey[hi];
      int ia = sidx[lo], ib = sidx[hi];
      bool hi_lt_lo = (kb < ka) || (kb == ka && ib < ia);
      bool lo_lt_hi = (ka < kb) || (ka == kb && ia < ib);
      if (asc ? hi_lt_lo : lo_lt_hi) {
        skey[lo] = kb; skey[hi] = ka;
        sidx[lo] = ib; sidx[hi] = ia;
      }
    }
  }
  __syncthreads();

  for (int r = tid; r < n; r += 1024) {
    int node = g * n + sidx[r];
    node_map[node] = (r < k) ? (g * k + r) : -1;
    if (r < k) perm[g * k + r] = node;
  }
}

// K3: x_out[row] = x[perm[row]] * gate[perm[row]]; batch_out.
__global__ __launch_bounds__(256) void gather_kernel(
    const float* __restrict__ x, const float* __restrict__ gate,
    const int* __restrict__ perm, float* __restrict__ x_out,
    float* __restrict__ batch_out, int total_rows, int k) {
  int t = (int)(blockIdx.x * 256u + threadIdx.x);
  int row = t >> 5;
  int d4 = t & 31;
  if (row >= total_rows) return;
  int src = perm[row];
  float s = gate[src];
  float4 v = *reinterpret_cast<const float4*>(x + (size_t)src * 128 + d4 * 4);
  v.x *= s; v.y *= s; v.z *= s; v.w *= s;
  *reinterpret_cast<float4*>(x_out + (size_t)row * 128 + d4 * 4) = v;
  if (d4 == 0) batch_out[row] = (float)(row / k);
}

// K4: fused edge remap + mask + attr gating, block-tiled for coalescing.
// Phase A: 256 threads -> 256 edge masks (coalesced idx reads, LDS mask).
// Phase B: 256 threads stream the block's 1024 float4 attrs contiguously.
__global__ __launch_bounds__(256) void edge_kernel(
    const int* __restrict__ edge_index, const int* __restrict__ node_map,
    const float4* __restrict__ attr, float* __restrict__ eio,
    float* __restrict__ mask_out, float4* __restrict__ attr_out, int E) {
  __shared__ float smask[256];
  const int base = (int)(blockIdx.x * 256u);
  const int e = base + threadIdx.x;
  int ns = node_map[edge_index[e]];
  int nd = node_map[edge_index[E + e]];
  bool m = (ns >= 0) && (nd >= 0);
  float z = m ? 1.0f : 0.0f;
  eio[e] = m ? (float)ns : -1.0f;
  eio[E + e] = m ? (float)nd : -1.0f;
  mask_out[e] = z;
  smask[threadIdx.x] = z;
  __syncthreads();
  const float4* ablk = attr + (size_t)base * 4;
  float4* oblk = attr_out + (size_t)base * 4;
#pragma unroll
  for (int it = 0; it < 4; ++it) {
    int idx = it * 256 + (int)threadIdx.x;   // 0..1023, lane-contiguous 16B
    float zz = smask[idx >> 2];
    float4 a = ablk[idx];
    a.x *= zz; a.y *= zz; a.z *= zz; a.w *= zz;
    oblk[idx] = a;
  }
}

extern "C" void kernel_launch(void* const* d_in, const int* in_sizes, int n_in,
                              void* d_out, int out_size, void* d_ws, size_t ws_size,
                              hipStream_t stream) {
  const float* x          = (const float*)d_in[0];
  const int*   edge_index = (const int*)d_in[1];
  const float* edge_attr  = (const float*)d_in[2];
  const float* w          = (const float*)d_in[4];

  const int D = 128;
  const int n_total = in_sizes[0] / D;         // 524288
  const int E = in_sizes[1] / 2;               // 4194304
  const int G = 256;
  const int n = n_total / G;                   // 2048
  const int k = (n + 1) / 2;                   // 1024
  const int total_rows = G * k;                // 262144

  float* out       = (float*)d_out;
  float* x_out     = out;
  float* eio       = x_out + (size_t)total_rows * D;
  float* attr_out  = eio + (size_t)2 * E;
  float* batch_out = attr_out + (size_t)E * 16;
  float* mask_out  = batch_out + total_rows;

  double* keys  = (double*)d_ws;                                    // 4 MB
  float* gate   = (float*)((char*)d_ws + (size_t)n_total * 8);      // 2 MB
  int* perm     = (int*)(gate + n_total);                           // 1 MB
  int* node_map = perm + total_rows;                                // 2 MB

  score_kernel<<<(n_total * 32) / 256, 256, 0, stream>>>(x, w, keys, gate, n_total);
  topk_kernel<<<G, 1024, 0, stream>>>(keys, perm, node_map, n, k);
  gather_kernel<<<(total_rows * 32) / 256, 256, 0, stream>>>(
      x, gate, perm, x_out, batch_out, total_rows, k);
  edge_kernel<<<E / 256, 256, 0, stream>>>(
      edge_index, node_map, (const float4*)edge_attr, eio, mask_out,
      (float4*)attr_out, E);
}